// Round 8
// baseline (117.075 us; speedup 1.0000x reference)
//
#include <hip/hip_runtime.h>
#include <cstdint>
#include <cmath>

#define B_ROWS 256
#define V_COLS 128000
#define CHUNKS 25
#define GSPLIT 13                  // chunks [0,GSPLIT) gumbel in K1, rest in K3
#define CHUNK_QUADS 1280           // V_COLS/4/CHUNKS; exactly 5 quads/thread
#define ATHREADS 256
#define AWAVES 4
#define QPT 5
#define ELEMS_PT 20
#define LN2F 0.69314718055994530942f

// ws float layout:
//  G region:  [row][chunk][4] = (Gv, Gi, M, S)         @ 0,      25600 floats
//  FIN:       [row][4]        = (M, invS, Gi, unused)  @ 25600,   1024 floats
//  S region:  [row][chunk][2] = (Sv, Si)               @ 26624,  12800 floats
#define G_STRIDE 4
#define FIN_OFF (B_ROWS * CHUNKS * G_STRIDE)
#define S_OFF (FIN_OFF + B_ROWS * 4)

__device__ __forceinline__ uint32_t rotl32(uint32_t x, uint32_t d) {
  return __builtin_amdgcn_alignbit(x, x, 32u - d);
}

// threefry2x32 key (0,42), XOR of outputs (JAX partitionable threefry).
__device__ __forceinline__ uint32_t threefry_xor(uint32_t x0, uint32_t x1) {
  const uint32_t k0 = 0u;
  const uint32_t k1 = 42u;
  const uint32_t k2 = 0x1BD11BDAu ^ k0 ^ k1;
  x0 += k0; x1 += k1;
#define TF_RND(r) { x0 += x1; x1 = rotl32(x1, (r)); x1 ^= x0; }
  TF_RND(13) TF_RND(15) TF_RND(26) TF_RND(6)
  x0 += k1; x1 += k2 + 1u;
  TF_RND(17) TF_RND(29) TF_RND(16) TF_RND(24)
  x0 += k2; x1 += k0 + 2u;
  TF_RND(13) TF_RND(15) TF_RND(26) TF_RND(6)
  x0 += k0; x1 += k1 + 3u;
  TF_RND(17) TF_RND(29) TF_RND(16) TF_RND(24)
  x0 += k1; x1 += k2 + 4u;
  TF_RND(13) TF_RND(15) TF_RND(26) TF_RND(6)
  x0 += k2; x1 += k0 + 5u;
#undef TF_RND
  return x0 ^ x1;
}

// gumbel = -LN2F * gumbel_l2(bits); caller folds into fma with sx
__device__ __forceinline__ float gumbel_l2(uint32_t bits) {
  uint32_t ub = (bits >> 9) | 0x3f800000u;
  float f = __uint_as_float(ub) - 1.0f;
  float u = fmaxf(f, 1.17549435e-38f);
  const float l1 = __log2f(u);
  const float nl = -LN2F * l1;
  return __log2f(nl);
}

// ---------- K1: softmax (M,S) + greedy + gumbel for chunks < GSPLIT ----------
__global__ __launch_bounds__(ATHREADS, 4) void pass1_kernel(
    const float* __restrict__ logits,
    const float* __restrict__ temps,
    float* __restrict__ ws) {
  const uint32_t bx = blockIdx.x;
  const uint32_t b = bx / CHUNKS;
  const uint32_t chunk = bx - b * CHUNKS;
  const int tid = threadIdx.x;
  const float t = temps[b];
  const float inv_t = (t == 0.0f) ? 1.0f : (1.0f / t);
  const float* __restrict__ row = logits + (size_t)b * V_COLS;
  const int q0 = (int)chunk * CHUNK_QUADS + tid;

  float4 xq[QPT];
#pragma unroll
  for (int j = 0; j < QPT; ++j)
    xq[j] = reinterpret_cast<const float4*>(row)[q0 + j * ATHREADS];

  float sx[ELEMS_PT];
#pragma unroll
  for (int j = 0; j < QPT; ++j) {
    sx[4 * j + 0] = xq[j].x * inv_t;
    sx[4 * j + 1] = xq[j].y * inv_t;
    sx[4 * j + 2] = xq[j].z * inv_t;
    sx[4 * j + 3] = xq[j].w * inv_t;
  }

  // greedy argmax over raw x; strict > + ascending order => first index wins
  float av = -INFINITY; int ai = 0;
  const int v0 = q0 * 4;
#pragma unroll
  for (int j = 0; j < QPT; ++j) {
    const float xa[4] = {xq[j].x, xq[j].y, xq[j].z, xq[j].w};
#pragma unroll
    for (int k = 0; k < 4; ++k) {
      const bool up = xa[k] > av;
      av = up ? xa[k] : av;
      ai = up ? (v0 + j * 1024 + k) : ai;
    }
  }

  // thread softmax vs mthr = av*inv_t (bitwise == max(sx), monotone rounding)
  const float mthr = av * inv_t;
  float s = 0.0f;
#pragma unroll
  for (int k = 0; k < ELEMS_PT; ++k) s += __expf(sx[k] - mthr);

  // gumbel argmax for this kernel's share of chunks (no global deps)
  float gv = -INFINITY; int gi = 0;
  const bool do_gumbel = (chunk < GSPLIT) && (t != 0.0f);
  if (do_gumbel) {
    const uint32_t cb = b * (uint32_t)V_COLS + (uint32_t)v0;
#pragma unroll
    for (int j = 0; j < QPT; ++j) {
#pragma unroll
      for (int k = 0; k < 4; ++k) {
        const float c = fmaf(-LN2F,
            gumbel_l2(threefry_xor(0u, cb + (uint32_t)(j * 1024 + k))),
            sx[4 * j + k]);
        const bool up = c > gv;
        gv = up ? c : gv;
        gi = up ? (v0 + j * 1024 + k) : gi;
      }
    }
  }

  float m = mthr;
#pragma unroll
  for (int off = 32; off > 0; off >>= 1) {
    float ov = __shfl_xor(av, off);
    int   oi = __shfl_xor(ai, off);
    if (ov > av || (ov == av && oi < ai)) { av = ov; ai = oi; }
    float o2v = __shfl_xor(gv, off);
    int   o2i = __shfl_xor(gi, off);
    if (o2v > gv || (o2v == gv && o2i < gi)) { gv = o2v; gi = o2i; }
    float om = __shfl_xor(m, off);
    float os = __shfl_xor(s, off);
    float mn = fmaxf(m, om);
    s = fmaf(s, __expf(m - mn), os * __expf(om - mn));
    m = mn;
  }

  __shared__ float lds_av[AWAVES]; __shared__ int lds_ai[AWAVES];
  __shared__ float lds_gv[AWAVES]; __shared__ int lds_gi[AWAVES];
  __shared__ float lds_m[AWAVES];  __shared__ float lds_s[AWAVES];
  const int wid = tid >> 6;
  if ((tid & 63) == 0) {
    lds_av[wid] = av; lds_ai[wid] = ai;
    lds_gv[wid] = gv; lds_gi[wid] = gi;
    lds_m[wid] = m;   lds_s[wid] = s;
  }
  __syncthreads();
  if (tid == 0) {
    float Av = lds_av[0]; int Ai = lds_ai[0];
    float Gv = lds_gv[0]; int Gi = lds_gi[0];
    float M = lds_m[0];   float S = lds_s[0];
#pragma unroll
    for (int w = 1; w < AWAVES; ++w) {
      float ov = lds_av[w]; int oi = lds_ai[w];
      if (ov > Av || (ov == Av && oi < Ai)) { Av = ov; Ai = oi; }
      float o2v = lds_gv[w]; int o2i = lds_gi[w];
      if (o2v > Gv || (o2v == Gv && o2i < Gi)) { Gv = o2v; Gi = o2i; }
      float om = lds_m[w]; float os = lds_s[w];
      float mn = fmaxf(M, om);
      S = fmaf(S, __expf(M - mn), os * __expf(om - mn));
      M = mn;
    }
    float* p = ws + (size_t)(b * CHUNKS + chunk) * G_STRIDE;
    p[0] = Av; p[1] = __int_as_float(Ai);
    p[2] = M;  p[3] = S;
    if (do_gumbel) {
      float* q = ws + S_OFF + (size_t)(b * CHUNKS + chunk) * 2;
      q[0] = Gv; q[1] = __int_as_float(Gi);
    }
  }
}

// ---------- K2: merge chunks -> per-row (M, invS, greedy idx) ----------
__global__ __launch_bounds__(B_ROWS) void fin1_kernel(
    float* __restrict__ ws) {
  const int r = threadIdx.x;
  const float* p = ws + (size_t)r * CHUNKS * G_STRIDE;
  float Av = -INFINITY; int Ai = 0;
  float M = -INFINITY;  float S = 0.0f;
#pragma unroll
  for (int c = 0; c < CHUNKS; ++c) {
    const float* q = p + c * G_STRIDE;
    float ov = q[0]; int oi = __float_as_int(q[1]);
    if (ov > Av) { Av = ov; Ai = oi; }   // ascending chunks: first index wins
    float om = q[2]; float os = q[3];
    float mn = fmaxf(M, om);
    S = fmaf(S, __expf(M - mn), os * __expf(om - mn));
    M = mn;
  }
  float* f = ws + FIN_OFF + 4 * r;
  f[0] = M;
  f[1] = 1.0f / S;
  f[2] = __int_as_float(Ai);
}

// ---------- K3: probs streaming + gumbel for chunks >= GSPLIT ----------
__global__ __launch_bounds__(ATHREADS, 4) void pass2_kernel(
    const float* __restrict__ logits,
    const float* __restrict__ temps,
    float* __restrict__ ws,
    float* __restrict__ out) {
  const uint32_t bx = blockIdx.x;
  const uint32_t b = bx / CHUNKS;
  const uint32_t chunk = bx - b * CHUNKS;
  const int tid = threadIdx.x;
  const float t = temps[b];
  const float inv_t = (t == 0.0f) ? 1.0f : (1.0f / t);
  const float M = ws[FIN_OFF + 4 * b + 0];
  const float invS = ws[FIN_OFF + 4 * b + 1];
  const float* __restrict__ row = logits + (size_t)b * V_COLS;
  float* __restrict__ prow = out + B_ROWS + (size_t)b * V_COLS;
  const int q0 = (int)chunk * CHUNK_QUADS + tid;

  float4 xq[QPT];
#pragma unroll
  for (int j = 0; j < QPT; ++j)
    xq[j] = reinterpret_cast<const float4*>(row)[q0 + j * ATHREADS];

  // probs stream: memory hides under the gumbel VALU below
#pragma unroll
  for (int j = 0; j < QPT; ++j) {
    float4 p4;
    p4.x = __expf(fmaf(xq[j].x, inv_t, -M)) * invS;
    p4.y = __expf(fmaf(xq[j].y, inv_t, -M)) * invS;
    p4.z = __expf(fmaf(xq[j].z, inv_t, -M)) * invS;
    p4.w = __expf(fmaf(xq[j].w, inv_t, -M)) * invS;
    reinterpret_cast<float4*>(prow)[q0 + j * ATHREADS] = p4;
  }

  const bool do_gumbel = (chunk >= GSPLIT) && (t != 0.0f);
  float gv = -INFINITY; int gi = 0;
  if (do_gumbel) {
    const int v0 = q0 * 4;
    const uint32_t cb = b * (uint32_t)V_COLS + (uint32_t)v0;
#pragma unroll
    for (int j = 0; j < QPT; ++j) {
      const float xa[4] = {xq[j].x, xq[j].y, xq[j].z, xq[j].w};
#pragma unroll
      for (int k = 0; k < 4; ++k) {
        const float sxv = xa[k] * inv_t;
        const float c = fmaf(-LN2F,
            gumbel_l2(threefry_xor(0u, cb + (uint32_t)(j * 1024 + k))), sxv);
        const bool up = c > gv;
        gv = up ? c : gv;
        gi = up ? (v0 + j * 1024 + k) : gi;
      }
    }

#pragma unroll
    for (int off = 32; off > 0; off >>= 1) {
      float ov = __shfl_xor(gv, off);
      int   oi = __shfl_xor(gi, off);
      if (ov > gv || (ov == gv && oi < gi)) { gv = ov; gi = oi; }
    }

    __shared__ float lds_gv[AWAVES]; __shared__ int lds_gi[AWAVES];
    const int wid = tid >> 6;
    if ((tid & 63) == 0) { lds_gv[wid] = gv; lds_gi[wid] = gi; }
    __syncthreads();
    if (tid == 0) {
      float Gv = lds_gv[0]; int Gi = lds_gi[0];
#pragma unroll
      for (int w = 1; w < AWAVES; ++w) {
        float ov = lds_gv[w]; int oi = lds_gi[w];
        if (ov > Gv || (ov == Gv && oi < Gi)) { Gv = ov; Gi = oi; }
      }
      float* p = ws + S_OFF + (size_t)(b * CHUNKS + chunk) * 2;
      p[0] = Gv; p[1] = __int_as_float(Gi);
    }
  }
}

// ---------- K4: merge sample partials -> tokens ----------
__global__ __launch_bounds__(B_ROWS) void fin2_kernel(
    const float* __restrict__ temps,
    const float* __restrict__ ws,
    float* __restrict__ out) {
  const int r = threadIdx.x;
  const float t = temps[r];
  int token;
  if (t == 0.0f) {
    token = __float_as_int(ws[FIN_OFF + 4 * r + 2]);   // greedy
  } else {
    const float* p = ws + S_OFF + (size_t)r * CHUNKS * 2;
    float Sv = -INFINITY; int Si = 0;
#pragma unroll
    for (int c = 0; c < CHUNKS; ++c) {
      float ov = p[2 * c]; int oi = __float_as_int(p[2 * c + 1]);
      if (ov > Sv) { Sv = ov; Si = oi; }   // ascending: first index wins
    }
    token = Si;
  }
  out[r] = (float)token;
}

extern "C" void kernel_launch(void* const* d_in, const int* in_sizes, int n_in,
                              void* d_out, int out_size, void* d_ws, size_t ws_size,
                              hipStream_t stream) {
  const float* logits = (const float*)d_in[0];
  const float* temps  = (const float*)d_in[1];
  float* out = (float*)d_out;
  float* ws  = (float*)d_ws;
  pass1_kernel<<<B_ROWS * CHUNKS, ATHREADS, 0, stream>>>(logits, temps, ws);
  fin1_kernel<<<1, B_ROWS, 0, stream>>>(ws);
  pass2_kernel<<<B_ROWS * CHUNKS, ATHREADS, 0, stream>>>(logits, temps, ws, out);
  fin2_kernel<<<1, B_ROWS, 0, stream>>>(temps, ws, out);
}

// Round 10
// 106.445 us; speedup vs baseline: 1.0999x; 1.0999x over previous
//
#include <hip/hip_runtime.h>
#include <cstdint>
#include <cmath>

#define B_ROWS 256
#define V_COLS 128000
#define CHUNKS 25
#define CHUNK_QUADS 1280           // V_COLS/4/CHUNKS; exactly 5 quads/thread
#define ATHREADS 256
#define AWAVES 4
#define QPT 5
#define ELEMS_PT 20
#define LN2F 0.69314718055994530942f
// gumbel range: u in [tiny, 1-2^-23] -> g in [-4.470, 15.944], window 20.41.
// Screen margin 21.2 > 20.41: elements with sx <= M-21.2 can never win.
#define GUMBEL_WINDOW 21.2f

// ws float layout:
//  G region:  [row][chunk][4] = (Gv, Gi, M, S)         @ 0,      25600 floats
//  FIN:       [row][4]        = (M, invS, Gi, unused)  @ 25600,   1024 floats
//  S region:  [row][chunk][2] = (Sv, Si)               @ 26624,  12800 floats
#define G_STRIDE 4
#define FIN_OFF (B_ROWS * CHUNKS * G_STRIDE)
#define S_OFF (FIN_OFF + B_ROWS * 4)

__device__ __forceinline__ uint32_t rotl32(uint32_t x, uint32_t d) {
  return __builtin_amdgcn_alignbit(x, x, 32u - d);
}

// threefry2x32 key (0,42), XOR of outputs (JAX partitionable threefry).
// Caller pre-adds k1=42 into x1 (x0 = 0+k0 = 0): bit-identical stream.
__device__ __forceinline__ uint32_t threefry_xor_pre(uint32_t x1) {
  const uint32_t k1 = 42u;
  const uint32_t k2 = 0x1BD11BF0u;   // 0x1BD11BDA ^ 0 ^ 42
  uint32_t x0 = 0u;
#define TF_RND(r) { x0 += x1; x1 = rotl32(x1, (r)); x1 ^= x0; }
  TF_RND(13) TF_RND(15) TF_RND(26) TF_RND(6)
  x0 += k1; x1 += k2 + 1u;
  TF_RND(17) TF_RND(29) TF_RND(16) TF_RND(24)
  x0 += k2; x1 += 0u + 2u;
  TF_RND(13) TF_RND(15) TF_RND(26) TF_RND(6)
  x0 += 0u; x1 += k1 + 3u;
  TF_RND(17) TF_RND(29) TF_RND(16) TF_RND(24)
  x0 += k1; x1 += k2 + 4u;
  TF_RND(13) TF_RND(15) TF_RND(26) TF_RND(6)
  x0 += k2; x1 += 0u + 5u;
#undef TF_RND
  return x0 ^ x1;
}

// gumbel = -LN2F * gumbel_l2(bits); caller folds into fma with sx
__device__ __forceinline__ float gumbel_l2(uint32_t bits) {
  uint32_t ub = (bits >> 9) | 0x3f800000u;
  float f = __uint_as_float(ub) - 1.0f;
  float u = fmaxf(f, 1.17549435e-38f);
  const float l1 = __log2f(u);
  const float nl = -LN2F * l1;
  return __log2f(nl);
}

// ---------- K1: softmax (M,S) + greedy argmax partials (no RNG) ----------
__global__ __launch_bounds__(ATHREADS, 4) void pass1_kernel(
    const float* __restrict__ logits,
    const float* __restrict__ temps,
    float* __restrict__ ws) {
  const uint32_t bx = blockIdx.x;
  const uint32_t b = bx / CHUNKS;
  const uint32_t chunk = bx - b * CHUNKS;
  const int tid = threadIdx.x;
  const float t = temps[b];
  const float inv_t = (t == 0.0f) ? 1.0f : (1.0f / t);
  const float* __restrict__ row = logits + (size_t)b * V_COLS;
  const int q0 = (int)chunk * CHUNK_QUADS + tid;

  float4 xq[QPT];
#pragma unroll
  for (int j = 0; j < QPT; ++j)
    xq[j] = reinterpret_cast<const float4*>(row)[q0 + j * ATHREADS];

  // greedy argmax over raw x; strict > + ascending order => first index wins
  float av = -INFINITY; int ai = 0;
  const int v0 = q0 * 4;
#pragma unroll
  for (int j = 0; j < QPT; ++j) {
    const float xa[4] = {xq[j].x, xq[j].y, xq[j].z, xq[j].w};
#pragma unroll
    for (int k = 0; k < 4; ++k) {
      const bool up = xa[k] > av;
      av = up ? xa[k] : av;
      ai = up ? (v0 + j * 1024 + k) : ai;
    }
  }

  // thread max of sx bitwise (mul by inv_t>0 is round-monotone)
  const float mthr = av * inv_t;
  float s = 0.0f;
#pragma unroll
  for (int j = 0; j < QPT; ++j) {
    s += __expf(fmaf(xq[j].x, inv_t, -mthr));
    s += __expf(fmaf(xq[j].y, inv_t, -mthr));
    s += __expf(fmaf(xq[j].z, inv_t, -mthr));
    s += __expf(fmaf(xq[j].w, inv_t, -mthr));
  }

  float m = mthr;
#pragma unroll
  for (int off = 32; off > 0; off >>= 1) {
    float ov = __shfl_xor(av, off);
    int   oi = __shfl_xor(ai, off);
    if (ov > av || (ov == av && oi < ai)) { av = ov; ai = oi; }
    float om = __shfl_xor(m, off);
    float os = __shfl_xor(s, off);
    float mn = fmaxf(m, om);
    s = fmaf(s, __expf(m - mn), os * __expf(om - mn));
    m = mn;
  }

  __shared__ float lds_av[AWAVES]; __shared__ int lds_ai[AWAVES];
  __shared__ float lds_m[AWAVES];  __shared__ float lds_s[AWAVES];
  const int wid = tid >> 6;
  if ((tid & 63) == 0) {
    lds_av[wid] = av; lds_ai[wid] = ai;
    lds_m[wid] = m;   lds_s[wid] = s;
  }
  __syncthreads();
  if (tid == 0) {
    float Av = lds_av[0]; int Ai = lds_ai[0];
    float M = lds_m[0];   float S = lds_s[0];
#pragma unroll
    for (int w = 1; w < AWAVES; ++w) {
      float ov = lds_av[w]; int oi = lds_ai[w];
      if (ov > Av || (ov == Av && oi < Ai)) { Av = ov; Ai = oi; }
      float om = lds_m[w]; float os = lds_s[w];
      float mn = fmaxf(M, om);
      S = fmaf(S, __expf(M - mn), os * __expf(om - mn));
      M = mn;
    }
    float* p = ws + (size_t)(b * CHUNKS + chunk) * G_STRIDE;
    p[0] = Av; p[1] = __int_as_float(Ai);
    p[2] = M;  p[3] = S;
  }
}

// ---------- K2: merge chunks -> per-row (M, invS, greedy idx) ----------
__global__ __launch_bounds__(B_ROWS) void fin1_kernel(
    float* __restrict__ ws) {
  const int r = threadIdx.x;
  const float* p = ws + (size_t)r * CHUNKS * G_STRIDE;
  float Av = -INFINITY; int Ai = 0;
  float M = -INFINITY;  float S = 0.0f;
#pragma unroll
  for (int c = 0; c < CHUNKS; ++c) {
    const float* q = p + c * G_STRIDE;
    float ov = q[0]; int oi = __float_as_int(q[1]);
    if (ov > Av) { Av = ov; Ai = oi; }   // ascending chunks: first index wins
    float om = q[2]; float os = q[3];
    float mn = fmaxf(M, om);
    S = fmaf(S, __expf(M - mn), os * __expf(om - mn));
    M = mn;
  }
  float* f = ws + FIN_OFF + 4 * r;
  f[0] = M;
  f[1] = 1.0f / S;
  f[2] = __int_as_float(Ai);
}

// ---------- K3: probs streaming + screened gumbel argmax (fused) ----------
__global__ __launch_bounds__(ATHREADS, 4) void pass2_kernel(
    const float* __restrict__ logits,
    const float* __restrict__ temps,
    float* __restrict__ ws,
    float* __restrict__ out) {
  const uint32_t bx = blockIdx.x;
  const uint32_t b = bx / CHUNKS;
  const uint32_t chunk = bx - b * CHUNKS;
  const int tid = threadIdx.x;
  const float t = temps[b];
  const float inv_t = (t == 0.0f) ? 1.0f : (1.0f / t);
  const float M = ws[FIN_OFF + 4 * b + 0];
  const float invS = ws[FIN_OFF + 4 * b + 1];
  const float* __restrict__ row = logits + (size_t)b * V_COLS;
  float* __restrict__ prow = out + B_ROWS + (size_t)b * V_COLS;
  const int q0 = (int)chunk * CHUNK_QUADS + tid;

  float4 xq[QPT];
#pragma unroll
  for (int j = 0; j < QPT; ++j)
    xq[j] = reinterpret_cast<const float4*>(row)[q0 + j * ATHREADS];

  // probs stream: memory hides under the gumbel VALU below
#pragma unroll
  for (int j = 0; j < QPT; ++j) {
    float4 p4;
    p4.x = __expf(fmaf(xq[j].x, inv_t, -M)) * invS;
    p4.y = __expf(fmaf(xq[j].y, inv_t, -M)) * invS;
    p4.z = __expf(fmaf(xq[j].z, inv_t, -M)) * invS;
    p4.w = __expf(fmaf(xq[j].w, inv_t, -M)) * invS;
    reinterpret_cast<float4*>(prow)[q0 + j * ATHREADS] = p4;
  }

  // gumbel argmax, screened: a quad-group is skipped when the whole wave's
  // sx values sit below M - 21.2 (bounded-gumbel argument; token-exact).
  float gv = -INFINITY; int gi = 0;
  if (t != 0.0f) {
    const int v0 = q0 * 4;
    const uint32_t cb42 = b * (uint32_t)V_COLS + (uint32_t)v0 + 42u;
    const float thrM = M - GUMBEL_WINDOW;
#pragma unroll
    for (int j = 0; j < QPT; ++j) {
      const float xa[4] = {xq[j].x, xq[j].y, xq[j].z, xq[j].w};
      const float mx4 = fmaxf(fmaxf(xa[0], xa[1]), fmaxf(xa[2], xa[3]));
      if (__any(mx4 * inv_t > thrM)) {
#pragma unroll
        for (int k = 0; k < 4; ++k) {
          const float sxv = xa[k] * inv_t;
          const float c = fmaf(-LN2F,
              gumbel_l2(threefry_xor_pre(cb42 + (uint32_t)(j * 1024 + k))),
              sxv);
          const bool up = c > gv;
          gv = up ? c : gv;
          gi = up ? (v0 + j * 1024 + k) : gi;
        }
      }
    }

#pragma unroll
    for (int off = 32; off > 0; off >>= 1) {
      float ov = __shfl_xor(gv, off);
      int   oi = __shfl_xor(gi, off);
      if (ov > gv || (ov == gv && oi < gi)) { gv = ov; gi = oi; }
    }

    __shared__ float lds_gv[AWAVES]; __shared__ int lds_gi[AWAVES];
    const int wid = tid >> 6;
    if ((tid & 63) == 0) { lds_gv[wid] = gv; lds_gi[wid] = gi; }
    __syncthreads();
    if (tid == 0) {
      float Gv = lds_gv[0]; int Gi = lds_gi[0];
#pragma unroll
      for (int w = 1; w < AWAVES; ++w) {
        float ov = lds_gv[w]; int oi = lds_gi[w];
        if (ov > Gv || (ov == Gv && oi < Gi)) { Gv = ov; Gi = oi; }
      }
      float* p = ws + S_OFF + (size_t)(b * CHUNKS + chunk) * 2;
      p[0] = Gv; p[1] = __int_as_float(Gi);
    }
  }
}

// ---------- K4: merge sample partials -> tokens ----------
__global__ __launch_bounds__(B_ROWS) void fin2_kernel(
    const float* __restrict__ temps,
    const float* __restrict__ ws,
    float* __restrict__ out) {
  const int r = threadIdx.x;
  const float t = temps[r];
  int token;
  if (t == 0.0f) {
    token = __float_as_int(ws[FIN_OFF + 4 * r + 2]);   // greedy
  } else {
    const float* p = ws + S_OFF + (size_t)r * CHUNKS * 2;
    float Sv = -INFINITY; int Si = 0;
#pragma unroll
    for (int c = 0; c < CHUNKS; ++c) {
      float ov = p[2 * c]; int oi = __float_as_int(p[2 * c + 1]);
      if (ov > Sv) { Sv = ov; Si = oi; }   // ascending: first index wins
    }
    token = Si;
  }
  out[r] = (float)token;
}

extern "C" void kernel_launch(void* const* d_in, const int* in_sizes, int n_in,
                              void* d_out, int out_size, void* d_ws, size_t ws_size,
                              hipStream_t stream) {
  const float* logits = (const float*)d_in[0];
  const float* temps  = (const float*)d_in[1];
  float* out = (float*)d_out;
  float* ws  = (float*)d_ws;
  pass1_kernel<<<B_ROWS * CHUNKS, ATHREADS, 0, stream>>>(logits, temps, ws);
  fin1_kernel<<<1, B_ROWS, 0, stream>>>(ws);
  pass2_kernel<<<B_ROWS * CHUNKS, ATHREADS, 0, stream>>>(logits, temps, ws, out);
  fin2_kernel<<<1, B_ROWS, 0, stream>>>(temps, ws, out);
}

// Round 11
// 102.987 us; speedup vs baseline: 1.1368x; 1.0336x over previous
//
#include <hip/hip_runtime.h>
#include <cstdint>
#include <cmath>

#define B_ROWS 256
#define V_COLS 128000
#define CHUNKS 25
#define CHUNK_QUADS 1280           // V_COLS/4/CHUNKS; exactly 5 quads/thread
#define ATHREADS 256
#define AWAVES 4
#define QPT 5
#define LN2F 0.69314718055994530942f
// gumbel range: u in [tiny, 1-2^-23] -> g in [-4.470, 15.944], window 20.41.
// Screen margin 21.2 > 20.41: elements with sx <= M-21.2 can never win.
#define GUMBEL_WINDOW 21.2f

// ws float layout:
//  G region:  [row][chunk][4] = (Gv, Gi, M, S)         @ 0,      25600 floats
//  FIN:       [row][4]        = (M, invS, Gi, unused)  @ 25600,   1024 floats
//  S region:  [row][chunk][2] = (Sv, Si)               @ 26624,  12800 floats
#define G_STRIDE 4
#define FIN_OFF (B_ROWS * CHUNKS * G_STRIDE)
#define S_OFF (FIN_OFF + B_ROWS * 4)

__device__ __forceinline__ uint32_t rotl32(uint32_t x, uint32_t d) {
  return __builtin_amdgcn_alignbit(x, x, 32u - d);
}

// threefry2x32 key (0,42), XOR of outputs (JAX partitionable threefry).
// Caller pre-adds k1=42 into x1 (x0 = 0+k0 = 0): bit-identical stream.
__device__ __forceinline__ uint32_t threefry_xor_pre(uint32_t x1) {
  const uint32_t k1 = 42u;
  const uint32_t k2 = 0x1BD11BF0u;   // 0x1BD11BDA ^ 0 ^ 42
  uint32_t x0 = 0u;
#define TF_RND(r) { x0 += x1; x1 = rotl32(x1, (r)); x1 ^= x0; }
  TF_RND(13) TF_RND(15) TF_RND(26) TF_RND(6)
  x0 += k1; x1 += k2 + 1u;
  TF_RND(17) TF_RND(29) TF_RND(16) TF_RND(24)
  x0 += k2; x1 += 0u + 2u;
  TF_RND(13) TF_RND(15) TF_RND(26) TF_RND(6)
  x0 += 0u; x1 += k1 + 3u;
  TF_RND(17) TF_RND(29) TF_RND(16) TF_RND(24)
  x0 += k1; x1 += k2 + 4u;
  TF_RND(13) TF_RND(15) TF_RND(26) TF_RND(6)
  x0 += k2; x1 += 0u + 5u;
#undef TF_RND
  return x0 ^ x1;
}

// gumbel = -LN2F * gumbel_l2(bits); caller folds into fma with sx
__device__ __forceinline__ float gumbel_l2(uint32_t bits) {
  uint32_t ub = (bits >> 9) | 0x3f800000u;
  float f = __uint_as_float(ub) - 1.0f;
  float u = fmaxf(f, 1.17549435e-38f);
  const float l1 = __log2f(u);
  const float nl = -LN2F * l1;
  return __log2f(nl);
}

// ---------- K1: softmax (M,S) + greedy argmax partials (no RNG) ----------
__global__ __launch_bounds__(ATHREADS, 2) void pass1_kernel(
    const float* __restrict__ logits,
    const float* __restrict__ temps,
    float* __restrict__ ws) {
  const uint32_t bx = blockIdx.x;
  const uint32_t b = bx / CHUNKS;
  const uint32_t chunk = bx - b * CHUNKS;
  const int tid = threadIdx.x;
  const float t = temps[b];
  const float inv_t = (t == 0.0f) ? 1.0f : (1.0f / t);
  const float* __restrict__ row = logits + (size_t)b * V_COLS;
  const int q0 = (int)chunk * CHUNK_QUADS + tid;

  float4 xq[QPT];
#pragma unroll
  for (int j = 0; j < QPT; ++j)
    xq[j] = reinterpret_cast<const float4*>(row)[q0 + j * ATHREADS];

  // greedy argmax over raw x; strict > + ascending order => first index wins
  float av = -INFINITY; int ai = 0;
  const int v0 = q0 * 4;
#pragma unroll
  for (int j = 0; j < QPT; ++j) {
    const float xa[4] = {xq[j].x, xq[j].y, xq[j].z, xq[j].w};
#pragma unroll
    for (int k = 0; k < 4; ++k) {
      const bool up = xa[k] > av;
      av = up ? xa[k] : av;
      ai = up ? (v0 + j * 1024 + k) : ai;
    }
  }

  // thread max of sx bitwise (mul by inv_t>0 is round-monotone)
  const float mthr = av * inv_t;
  float s = 0.0f;
#pragma unroll
  for (int j = 0; j < QPT; ++j) {
    s += __expf(fmaf(xq[j].x, inv_t, -mthr));
    s += __expf(fmaf(xq[j].y, inv_t, -mthr));
    s += __expf(fmaf(xq[j].z, inv_t, -mthr));
    s += __expf(fmaf(xq[j].w, inv_t, -mthr));
  }

  float m = mthr;
#pragma unroll
  for (int off = 32; off > 0; off >>= 1) {
    float ov = __shfl_xor(av, off);
    int   oi = __shfl_xor(ai, off);
    if (ov > av || (ov == av && oi < ai)) { av = ov; ai = oi; }
    float om = __shfl_xor(m, off);
    float os = __shfl_xor(s, off);
    float mn = fmaxf(m, om);
    s = fmaf(s, __expf(m - mn), os * __expf(om - mn));
    m = mn;
  }

  __shared__ float lds_av[AWAVES]; __shared__ int lds_ai[AWAVES];
  __shared__ float lds_m[AWAVES];  __shared__ float lds_s[AWAVES];
  const int wid = tid >> 6;
  if ((tid & 63) == 0) {
    lds_av[wid] = av; lds_ai[wid] = ai;
    lds_m[wid] = m;   lds_s[wid] = s;
  }
  __syncthreads();
  if (tid == 0) {
    float Av = lds_av[0]; int Ai = lds_ai[0];
    float M = lds_m[0];   float S = lds_s[0];
#pragma unroll
    for (int w = 1; w < AWAVES; ++w) {
      float ov = lds_av[w]; int oi = lds_ai[w];
      if (ov > Av || (ov == Av && oi < Ai)) { Av = ov; Ai = oi; }
      float om = lds_m[w]; float os = lds_s[w];
      float mn = fmaxf(M, om);
      S = fmaf(S, __expf(M - mn), os * __expf(om - mn));
      M = mn;
    }
    float* p = ws + (size_t)(b * CHUNKS + chunk) * G_STRIDE;
    p[0] = Av; p[1] = __int_as_float(Ai);
    p[2] = M;  p[3] = S;
  }
}

// ---------- K2: merge chunks -> per-row (M, invS, greedy idx) ----------
__global__ __launch_bounds__(B_ROWS) void fin1_kernel(
    float* __restrict__ ws) {
  const int r = threadIdx.x;
  const float* p = ws + (size_t)r * CHUNKS * G_STRIDE;
  float Av = -INFINITY; int Ai = 0;
  float M = -INFINITY;  float S = 0.0f;
#pragma unroll
  for (int c = 0; c < CHUNKS; ++c) {
    const float* q = p + c * G_STRIDE;
    float ov = q[0]; int oi = __float_as_int(q[1]);
    if (ov > Av) { Av = ov; Ai = oi; }   // ascending chunks: first index wins
    float om = q[2]; float os = q[3];
    float mn = fmaxf(M, om);
    S = fmaf(S, __expf(M - mn), os * __expf(om - mn));
    M = mn;
  }
  float* f = ws + FIN_OFF + 4 * r;
  f[0] = M;
  f[1] = 1.0f / S;
  f[2] = __int_as_float(Ai);
}

// ---------- K3: fused probs + screened gumbel, one load per quad ----------
__global__ __launch_bounds__(ATHREADS, 2) void pass2_kernel(
    const float* __restrict__ logits,
    const float* __restrict__ temps,
    float* __restrict__ ws,
    float* __restrict__ out) {
  const uint32_t bx = blockIdx.x;
  const uint32_t b = bx / CHUNKS;
  const uint32_t chunk = bx - b * CHUNKS;
  const int tid = threadIdx.x;
  const float t = temps[b];
  const float inv_t = (t == 0.0f) ? 1.0f : (1.0f / t);
  const float M = ws[FIN_OFF + 4 * b + 0];
  const float invS = ws[FIN_OFF + 4 * b + 1];
  const float* __restrict__ row = logits + (size_t)b * V_COLS;
  float* __restrict__ prow = out + B_ROWS + (size_t)b * V_COLS;
  const int q0 = (int)chunk * CHUNK_QUADS + tid;
  const int v0 = q0 * 4;
  const uint32_t cb42 = b * (uint32_t)V_COLS + (uint32_t)v0 + 42u;
  const float thrM = M - GUMBEL_WINDOW;

  float gv = -INFINITY; int gi = 0;

  if (t != 0.0f) {
#pragma unroll
    for (int j = 0; j < QPT; ++j) {
      const float4 x4 = reinterpret_cast<const float4*>(row)[q0 + j * ATHREADS];
      // probs (byte-identical formula)
      float4 p4;
      p4.x = __expf(fmaf(x4.x, inv_t, -M)) * invS;
      p4.y = __expf(fmaf(x4.y, inv_t, -M)) * invS;
      p4.z = __expf(fmaf(x4.z, inv_t, -M)) * invS;
      p4.w = __expf(fmaf(x4.w, inv_t, -M)) * invS;
      reinterpret_cast<float4*>(prow)[q0 + j * ATHREADS] = p4;
      // screened gumbel on the same registers
      const float xa[4] = {x4.x, x4.y, x4.z, x4.w};
      const float mx4 = fmaxf(fmaxf(xa[0], xa[1]), fmaxf(xa[2], xa[3]));
      if (__any(mx4 * inv_t > thrM)) {
#pragma unroll
        for (int k = 0; k < 4; ++k) {
          const float sxv = xa[k] * inv_t;
          const float c = fmaf(-LN2F,
              gumbel_l2(threefry_xor_pre(cb42 + (uint32_t)(j * 1024 + k))),
              sxv);
          const bool up = c > gv;
          gv = up ? c : gv;
          gi = up ? (v0 + j * 1024 + k) : gi;
        }
      }
    }

#pragma unroll
    for (int off = 32; off > 0; off >>= 1) {
      float ov = __shfl_xor(gv, off);
      int   oi = __shfl_xor(gi, off);
      if (ov > gv || (ov == gv && oi < gi)) { gv = ov; gi = oi; }
    }

    __shared__ float lds_gv[AWAVES]; __shared__ int lds_gi[AWAVES];
    const int wid = tid >> 6;
    if ((tid & 63) == 0) { lds_gv[wid] = gv; lds_gi[wid] = gi; }
    __syncthreads();
    if (tid == 0) {
      float Gv = lds_gv[0]; int Gi = lds_gi[0];
#pragma unroll
      for (int w = 1; w < AWAVES; ++w) {
        float ov = lds_gv[w]; int oi = lds_gi[w];
        if (ov > Gv || (ov == Gv && oi < Gi)) { Gv = ov; Gi = oi; }
      }
      float* p = ws + S_OFF + (size_t)(b * CHUNKS + chunk) * 2;
      p[0] = Gv; p[1] = __int_as_float(Gi);
    }
  } else {
    // greedy row: probs only
#pragma unroll
    for (int j = 0; j < QPT; ++j) {
      const float4 x4 = reinterpret_cast<const float4*>(row)[q0 + j * ATHREADS];
      float4 p4;
      p4.x = __expf(fmaf(x4.x, inv_t, -M)) * invS;
      p4.y = __expf(fmaf(x4.y, inv_t, -M)) * invS;
      p4.z = __expf(fmaf(x4.z, inv_t, -M)) * invS;
      p4.w = __expf(fmaf(x4.w, inv_t, -M)) * invS;
      reinterpret_cast<float4*>(prow)[q0 + j * ATHREADS] = p4;
    }
  }
}

// ---------- K4: merge sample partials -> tokens ----------
__global__ __launch_bounds__(B_ROWS) void fin2_kernel(
    const float* __restrict__ temps,
    const float* __restrict__ ws,
    float* __restrict__ out) {
  const int r = threadIdx.x;
  const float t = temps[r];
  int token;
  if (t == 0.0f) {
    token = __float_as_int(ws[FIN_OFF + 4 * r + 2]);   // greedy
  } else {
    const float* p = ws + S_OFF + (size_t)r * CHUNKS * 2;
    float Sv = -INFINITY; int Si = 0;
#pragma unroll
    for (int c = 0; c < CHUNKS; ++c) {
      float ov = p[2 * c]; int oi = __float_as_int(p[2 * c + 1]);
      if (ov > Sv) { Sv = ov; Si = oi; }   // ascending: first index wins
    }
    token = Si;
  }
  out[r] = (float)token;
}

extern "C" void kernel_launch(void* const* d_in, const int* in_sizes, int n_in,
                              void* d_out, int out_size, void* d_ws, size_t ws_size,
                              hipStream_t stream) {
  const float* logits = (const float*)d_in[0];
  const float* temps  = (const float*)d_in[1];
  float* out = (float*)d_out;
  float* ws  = (float*)d_ws;
  pass1_kernel<<<B_ROWS * CHUNKS, ATHREADS, 0, stream>>>(logits, temps, ws);
  fin1_kernel<<<1, B_ROWS, 0, stream>>>(ws);
  pass2_kernel<<<B_ROWS * CHUNKS, ATHREADS, 0, stream>>>(logits, temps, ws, out);
  fin2_kernel<<<1, B_ROWS, 0, stream>>>(temps, ws, out);
}

// Round 12
// 102.901 us; speedup vs baseline: 1.1377x; 1.0008x over previous
//
#include <hip/hip_runtime.h>
#include <cstdint>
#include <cmath>

#define B_ROWS 256
#define V_COLS 128000
#define CHUNKS 25
#define CHUNK_QUADS 1280           // V_COLS/4/CHUNKS; exactly 5 quads/thread
#define ATHREADS 256
#define AWAVES 4
#define QPT 5
#define LN2F 0.69314718055994530942f
// gumbel range: u in [tiny, 1-2^-23] -> g in [-4.470, 15.944], window 20.41.
// Screen margin 21.2 > 20.41: elements with sx <= M-21.2 can never win.
// (Screen is in sx-space; unaffected by the constant dropped in gumbel_ll2.)
#define GUMBEL_WINDOW 21.2f

// ws float layout:
//  G region:  [row][chunk][4] = (Gv, Gi, M, S)         @ 0,      25600 floats
//  FIN:       [row][4]        = (M, invS, Gi, unused)  @ 25600,   1024 floats
//  S region:  [row][chunk][2] = (Sv, Si)               @ 26624,  12800 floats
#define G_STRIDE 4
#define FIN_OFF (B_ROWS * CHUNKS * G_STRIDE)
#define S_OFF (FIN_OFF + B_ROWS * 4)

__device__ __forceinline__ uint32_t rotl32(uint32_t x, uint32_t d) {
  return __builtin_amdgcn_alignbit(x, x, 32u - d);
}

// threefry2x32 key (0,42), XOR of outputs (JAX partitionable threefry).
// Caller pre-adds k1=42 into x1 (x0 = 0+k0 = 0): bit-identical stream.
// (x0 starts at compile-time 0: LLVM folds round-1's x0+=x1.)
__device__ __forceinline__ uint32_t threefry_xor_pre(uint32_t x1) {
  const uint32_t k1 = 42u;
  const uint32_t k2 = 0x1BD11BF0u;   // 0x1BD11BDA ^ 0 ^ 42
  uint32_t x0 = 0u;
#define TF_RND(r) { x0 += x1; x1 = rotl32(x1, (r)); x1 ^= x0; }
  TF_RND(13) TF_RND(15) TF_RND(26) TF_RND(6)
  x0 += k1; x1 += k2 + 1u;
  TF_RND(17) TF_RND(29) TF_RND(16) TF_RND(24)
  x0 += k2; x1 += 0u + 2u;
  TF_RND(13) TF_RND(15) TF_RND(26) TF_RND(6)
  x0 += 0u; x1 += k1 + 3u;
  TF_RND(17) TF_RND(29) TF_RND(16) TF_RND(24)
  x0 += k1; x1 += k2 + 4u;
  TF_RND(13) TF_RND(15) TF_RND(26) TF_RND(6)
  x0 += k2; x1 += 0u + 5u;
#undef TF_RND
  return x0 ^ x1;
}

// Rank-equivalent gumbel: -ln(-ln u) = -LN2F*log2(-log2 u) - LN2F*log2(ln 2).
// The trailing constant is identical for every candidate, so dropping it
// preserves the argmax. Caller computes c = fmaf(-LN2F, ll2, sx).
__device__ __forceinline__ float gumbel_ll2(uint32_t bits) {
  uint32_t ub = (bits >> 9) | 0x3f800000u;
  float f = __uint_as_float(ub) - 1.0f;
  float u = fmaxf(f, 1.17549435e-38f);
  return __log2f(-__log2f(u));
}

// ---------- K1: softmax (M,S) + greedy argmax partials (no RNG) ----------
__global__ __launch_bounds__(ATHREADS) void pass1_kernel(
    const float* __restrict__ logits,
    const float* __restrict__ temps,
    float* __restrict__ ws) {
  const uint32_t bx = blockIdx.x;
  const uint32_t b = bx / CHUNKS;
  const uint32_t chunk = bx - b * CHUNKS;
  const int tid = threadIdx.x;
  const float t = temps[b];
  const float inv_t = (t == 0.0f) ? 1.0f : (1.0f / t);
  const float* __restrict__ row = logits + (size_t)b * V_COLS;
  const int q0 = (int)chunk * CHUNK_QUADS + tid;

  float4 xq[QPT];
#pragma unroll
  for (int j = 0; j < QPT; ++j)
    xq[j] = reinterpret_cast<const float4*>(row)[q0 + j * ATHREADS];

  // greedy argmax over raw x; strict > + ascending order => first index wins
  float av = -INFINITY; int ai = 0;
  const int v0 = q0 * 4;
#pragma unroll
  for (int j = 0; j < QPT; ++j) {
    const float xa[4] = {xq[j].x, xq[j].y, xq[j].z, xq[j].w};
#pragma unroll
    for (int k = 0; k < 4; ++k) {
      const bool up = xa[k] > av;
      av = up ? xa[k] : av;
      ai = up ? (v0 + j * 1024 + k) : ai;
    }
  }

  // thread max of sx bitwise (mul by inv_t>0 is round-monotone)
  const float mthr = av * inv_t;
  float s = 0.0f;
#pragma unroll
  for (int j = 0; j < QPT; ++j) {
    s += __expf(fmaf(xq[j].x, inv_t, -mthr));
    s += __expf(fmaf(xq[j].y, inv_t, -mthr));
    s += __expf(fmaf(xq[j].z, inv_t, -mthr));
    s += __expf(fmaf(xq[j].w, inv_t, -mthr));
  }

  float m = mthr;
#pragma unroll
  for (int off = 32; off > 0; off >>= 1) {
    float ov = __shfl_xor(av, off);
    int   oi = __shfl_xor(ai, off);
    if (ov > av || (ov == av && oi < ai)) { av = ov; ai = oi; }
    float om = __shfl_xor(m, off);
    float os = __shfl_xor(s, off);
    float mn = fmaxf(m, om);
    s = fmaf(s, __expf(m - mn), os * __expf(om - mn));
    m = mn;
  }

  __shared__ float lds_av[AWAVES]; __shared__ int lds_ai[AWAVES];
  __shared__ float lds_m[AWAVES];  __shared__ float lds_s[AWAVES];
  const int wid = tid >> 6;
  if ((tid & 63) == 0) {
    lds_av[wid] = av; lds_ai[wid] = ai;
    lds_m[wid] = m;   lds_s[wid] = s;
  }
  __syncthreads();
  if (tid == 0) {
    float Av = lds_av[0]; int Ai = lds_ai[0];
    float M = lds_m[0];   float S = lds_s[0];
#pragma unroll
    for (int w = 1; w < AWAVES; ++w) {
      float ov = lds_av[w]; int oi = lds_ai[w];
      if (ov > Av || (ov == Av && oi < Ai)) { Av = ov; Ai = oi; }
      float om = lds_m[w]; float os = lds_s[w];
      float mn = fmaxf(M, om);
      S = fmaf(S, __expf(M - mn), os * __expf(om - mn));
      M = mn;
    }
    float* p = ws + (size_t)(b * CHUNKS + chunk) * G_STRIDE;
    p[0] = Av; p[1] = __int_as_float(Ai);
    p[2] = M;  p[3] = S;
  }
}

// ---------- K2: merge chunks -> per-row (M, invS, greedy idx) ----------
__global__ __launch_bounds__(B_ROWS) void fin1_kernel(
    float* __restrict__ ws) {
  const int r = threadIdx.x;
  const float* p = ws + (size_t)r * CHUNKS * G_STRIDE;
  float Av = -INFINITY; int Ai = 0;
  float M = -INFINITY;  float S = 0.0f;
#pragma unroll
  for (int c = 0; c < CHUNKS; ++c) {
    const float* q = p + c * G_STRIDE;
    float ov = q[0]; int oi = __float_as_int(q[1]);
    if (ov > Av) { Av = ov; Ai = oi; }   // ascending chunks: first index wins
    float om = q[2]; float os = q[3];
    float mn = fmaxf(M, om);
    S = fmaf(S, __expf(M - mn), os * __expf(om - mn));
    M = mn;
  }
  float* f = ws + FIN_OFF + 4 * r;
  f[0] = M;
  f[1] = 1.0f / S;
  f[2] = __int_as_float(Ai);
}

// ---------- K3: fused probs + screened gumbel, one load per quad ----------
__global__ __launch_bounds__(ATHREADS) void pass2_kernel(
    const float* __restrict__ logits,
    const float* __restrict__ temps,
    float* __restrict__ ws,
    float* __restrict__ out) {
  const uint32_t bx = blockIdx.x;
  const uint32_t b = bx / CHUNKS;
  const uint32_t chunk = bx - b * CHUNKS;
  const int tid = threadIdx.x;
  const float t = temps[b];
  const float inv_t = (t == 0.0f) ? 1.0f : (1.0f / t);
  const float M = ws[FIN_OFF + 4 * b + 0];
  const float invS = ws[FIN_OFF + 4 * b + 1];
  const float* __restrict__ row = logits + (size_t)b * V_COLS;
  float* __restrict__ prow = out + B_ROWS + (size_t)b * V_COLS;
  const int q0 = (int)chunk * CHUNK_QUADS + tid;
  const int v0 = q0 * 4;
  const uint32_t cb42 = b * (uint32_t)V_COLS + (uint32_t)v0 + 42u;
  const float thrM = M - GUMBEL_WINDOW;

  float gv = -INFINITY; int gi = 0;

  if (t != 0.0f) {
#pragma unroll
    for (int j = 0; j < QPT; ++j) {
      const float4 x4 = reinterpret_cast<const float4*>(row)[q0 + j * ATHREADS];
      // probs (byte-identical formula)
      float4 p4;
      p4.x = __expf(fmaf(x4.x, inv_t, -M)) * invS;
      p4.y = __expf(fmaf(x4.y, inv_t, -M)) * invS;
      p4.z = __expf(fmaf(x4.z, inv_t, -M)) * invS;
      p4.w = __expf(fmaf(x4.w, inv_t, -M)) * invS;
      reinterpret_cast<float4*>(prow)[q0 + j * ATHREADS] = p4;
      // screened gumbel on the same registers
      const float xa[4] = {x4.x, x4.y, x4.z, x4.w};
      const float mx4 = fmaxf(fmaxf(xa[0], xa[1]), fmaxf(xa[2], xa[3]));
      if (__any(mx4 * inv_t > thrM)) {
#pragma unroll
        for (int k = 0; k < 4; ++k) {
          const float sxv = xa[k] * inv_t;
          const float c = fmaf(-LN2F,
              gumbel_ll2(threefry_xor_pre(cb42 + (uint32_t)(j * 1024 + k))),
              sxv);
          const bool up = c > gv;
          gv = up ? c : gv;
          gi = up ? (v0 + j * 1024 + k) : gi;
        }
      }
    }

#pragma unroll
    for (int off = 32; off > 0; off >>= 1) {
      float ov = __shfl_xor(gv, off);
      int   oi = __shfl_xor(gi, off);
      if (ov > gv || (ov == gv && oi < gi)) { gv = ov; gi = oi; }
    }

    __shared__ float lds_gv[AWAVES]; __shared__ int lds_gi[AWAVES];
    const int wid = tid >> 6;
    if ((tid & 63) == 0) { lds_gv[wid] = gv; lds_gi[wid] = gi; }
    __syncthreads();
    if (tid == 0) {
      float Gv = lds_gv[0]; int Gi = lds_gi[0];
#pragma unroll
      for (int w = 1; w < AWAVES; ++w) {
        float ov = lds_gv[w]; int oi = lds_gi[w];
        if (ov > Gv || (ov == Gv && oi < Gi)) { Gv = ov; Gi = oi; }
      }
      float* p = ws + S_OFF + (size_t)(b * CHUNKS + chunk) * 2;
      p[0] = Gv; p[1] = __int_as_float(Gi);
    }
  } else {
    // greedy row: probs only
#pragma unroll
    for (int j = 0; j < QPT; ++j) {
      const float4 x4 = reinterpret_cast<const float4*>(row)[q0 + j * ATHREADS];
      float4 p4;
      p4.x = __expf(fmaf(x4.x, inv_t, -M)) * invS;
      p4.y = __expf(fmaf(x4.y, inv_t, -M)) * invS;
      p4.z = __expf(fmaf(x4.z, inv_t, -M)) * invS;
      p4.w = __expf(fmaf(x4.w, inv_t, -M)) * invS;
      reinterpret_cast<float4*>(prow)[q0 + j * ATHREADS] = p4;
    }
  }
}

// ---------- K4: merge sample partials -> tokens ----------
__global__ __launch_bounds__(B_ROWS) void fin2_kernel(
    const float* __restrict__ temps,
    const float* __restrict__ ws,
    float* __restrict__ out) {
  const int r = threadIdx.x;
  const float t = temps[r];
  int token;
  if (t == 0.0f) {
    token = __float_as_int(ws[FIN_OFF + 4 * r + 2]);   // greedy
  } else {
    const float* p = ws + S_OFF + (size_t)r * CHUNKS * 2;
    float Sv = -INFINITY; int Si = 0;
#pragma unroll
    for (int c = 0; c < CHUNKS; ++c) {
      float ov = p[2 * c]; int oi = __float_as_int(p[2 * c + 1]);
      if (ov > Sv) { Sv = ov; Si = oi; }   // ascending: first index wins
    }
    token = Si;
  }
  out[r] = (float)token;
}

extern "C" void kernel_launch(void* const* d_in, const int* in_sizes, int n_in,
                              void* d_out, int out_size, void* d_ws, size_t ws_size,
                              hipStream_t stream) {
  const float* logits = (const float*)d_in[0];
  const float* temps  = (const float*)d_in[1];
  float* out = (float*)d_out;
  float* ws  = (float*)d_ws;
  pass1_kernel<<<B_ROWS * CHUNKS, ATHREADS, 0, stream>>>(logits, temps, ws);
  fin1_kernel<<<1, B_ROWS, 0, stream>>>(ws);
  pass2_kernel<<<B_ROWS * CHUNKS, ATHREADS, 0, stream>>>(logits, temps, ws, out);
  fin2_kernel<<<1, B_ROWS, 0, stream>>>(temps, ws, out);
}